// Round 9
// baseline (169.240 us; speedup 1.0000x reference)
//
#include <hip/hip_runtime.h>

#define Bdim 16
#define Sdim 16
#define Edim 256
#define Hdim 512
#define Vdim 16000
#define THR1f 0.8f
#define THR2f 1.0f

typedef unsigned int   u32;
typedef unsigned short u16;
typedef __attribute__((ext_vector_type(8))) short bf16x8;
typedef __attribute__((ext_vector_type(4))) float f32x4;
typedef __attribute__((ext_vector_type(4))) u32   u32x4;

__device__ __forceinline__ u16 f2bf(float f) {          // RNE fp32->bf16
  u32 u = __float_as_uint(f);
  return (u16)((u + 0x7FFFu + ((u >> 16) & 1u)) >> 16);
}
__device__ __forceinline__ u32 pack2(float a, float b) {
  return (u32)f2bf(a) | ((u32)f2bf(b) << 16);
}

// ---------------------------------------------------------------------------
// K1: prep = cur1 GEMM (fp32, exact) + m1 Leaky recurrence (fp32, exact).
// UNCHANGED (verified R7/R8). Emits Ab3 fragment-contiguous:
//   value(A-row r=32t+2b+c, col h) at ((S*32+R)*64+l)*8+j,
//   S=h>>5, R=r>>4, l=((h>>3)&3)*16+(r&15), j=h&7.
// ---------------------------------------------------------------------------
__global__ __launch_bounds__(256) void snn_prep(
    const int* __restrict__ x, const float* __restrict__ embed_w,
    const float* __restrict__ fc1_w, const float* __restrict__ fc1_b,
    const float* __restrict__ beta1p, const int* __restrict__ tsp,
    u16* __restrict__ Ab3, float* __restrict__ mem1)
{
  __shared__ __align__(16) float As[64][68];
  __shared__ __align__(16) float Ws[64][68];
  __shared__ float cbuf[64][68];
  __shared__ int sidx[64];
  const int tid = threadIdx.x;
  const int n0  = blockIdx.x * 64;       // h tile
  const int bi0 = blockIdx.y * 4;        // b tile
  const int tx = tid & 15, ty = tid >> 4;

  if (tid < 64) sidx[tid] = x[(bi0 + (tid & 3)) * Sdim + (tid >> 2)];

  float acc[4][4] = {{0.f}};
  for (int k0 = 0; k0 < Edim; k0 += 64) {
    __syncthreads();                     // also covers sidx on iter 0
#pragma unroll
    for (int i = 0; i < 16; ++i) {
      const int k = tid + i * 256;
      const int rr = k >> 6, j = k & 63;
      As[j][rr] = embed_w[(size_t)sidx[rr] * Edim + k0 + j];
      Ws[j][rr] = fc1_w[(size_t)(n0 + rr) * Edim + k0 + j];
    }
    __syncthreads();
#pragma unroll
    for (int j = 0; j < 64; ++j) {
      const float4 av = *(const float4*)&As[j][ty * 4];
      const float4 wv = *(const float4*)&Ws[j][tx * 4];
      const float a[4] = {av.x, av.y, av.z, av.w};
      const float w[4] = {wv.x, wv.y, wv.z, wv.w};
#pragma unroll
      for (int i = 0; i < 4; ++i)
#pragma unroll
        for (int jj = 0; jj < 4; ++jj)
          acc[i][jj] = fmaf(a[i], w[jj], acc[i][jj]);
    }
  }
#pragma unroll
  for (int i = 0; i < 4; ++i)
#pragma unroll
    for (int jj = 0; jj < 4; ++jj)
      cbuf[ty * 4 + i][tx * 4 + jj] = acc[i][jj] + fc1_b[n0 + tx * 4 + jj];
  __syncthreads();

  const int bb = tid >> 6, hl = tid & 63;
  const int b  = bi0 + bb;
  const int hg = n0 + hl;
  const float b1 = fminf(fmaxf(beta1p[0], 0.f), 1.f);
  const int T = tsp[0];

  double w9T = 1.0, w8T = 1.0;
  for (int i = 0; i < T; ++i) { w9T *= 0.9; w8T *= 0.8; }

  const int S = hg >> 5, q = (hg >> 3) & 3, jc = hg & 7;

  float m1 = 0.f;
  for (int t = 0; t < Sdim; ++t) {
    const float cur = cbuf[t * 4 + bb][hl];
    double p9 = w9T, p8 = w8T;
    float cs = 0.f, cm = 0.f;
    for (int u = 0; u < T; ++u) {
      const float reset = (m1 > THR1f) ? THR1f : 0.f;
      m1 = b1 * m1 + cur - reset;
      if (m1 > THR1f) {
        cs += (float)(p9 * (10.0 / 9.0));
        cm += (float)(10.0 * (p9 - p8));
      }
      p9 *= (10.0 / 9.0);
      p8 *= 1.25;
    }
    int rb = 2 * b;
    int R  = 2 * t + (rb >> 4);
    int l  = q * 16 + (rb & 15);
    Ab3[((size_t)(S * 32 + R) * 64 + l) * 8 + jc] = f2bf(cs);
    rb = 2 * b + 1;
    R  = 2 * t + (rb >> 4);
    l  = q * 16 + (rb & 15);
    Ab3[((size_t)(S * 32 + R) * 64 + l) * 8 + jc] = f2bf(cm);
  }
  mem1[b * Hdim + hg] = m1;
}

// ---------------------------------------------------------------------------
// K2: fused GEMM + Synaptic recurrence + spikes.  v5:
// 250 blocks x 8 waves (512 thr). Wave wr: rows 64wr..64wr+63 x ALL 64 cols
// (acc 4x4 frags = 64 VGPR), full K. A rows disjoint across waves -> A read
// once per block (128 MB L2 total). W-tile (128 KB) read by all 8 waves
// (HBM once, L2 re-hits). NO LDS / NO barriers in GEMM; next-S ping-pong
// prefetch, fully static. Epilogue: 8-stage t-relay (wave wr: t=2wr,2wr+1)
// via 8 KB LDS; mapping = v3/v4-verified b=8hi+2g+j, gs=acc[2tt+hi][cf][2j].
// ---------------------------------------------------------------------------
__global__ __launch_bounds__(512, 2) void snn_fused(
    const u16* __restrict__ Ab3, const float* __restrict__ W,
    const float* __restrict__ fc2_b, const int* __restrict__ tsp,
    float* __restrict__ out, float* __restrict__ syn2, float* __restrict__ mem2)
{
  __shared__ float2 st[16][64];          // [b][col] 8 KB relay state
  const int tid  = threadIdx.x;          // 0..511
  const int lane = tid & 63;
  const int wr   = tid >> 6;             // 0..7: rows 64wr..64wr+63
  const int v0   = blockIdx.x * 64;
  const int col  = lane & 15;
  const int grp  = lane >> 4;            // k-subchunk 8*grp

  f32x4 acc[4][4];                       // [i = local R][cf = col-frag]
#pragma unroll
  for (int i = 0; i < 4; ++i)
#pragma unroll
    for (int c = 0; c < 4; ++c)
#pragma unroll
      for (int e = 0; e < 4; ++e) acc[i][c][e] = 0.f;

  // A fragment bytes: (S*32 + 4wr + i)*1024 + lane*16
  const char* abase = (const char*)Ab3 + (wr << 12) + lane * 16;
  // W row pointers per col-frag
  const float* wp0 = W + (size_t)(v0 + 0  + col) * Hdim + grp * 8;
  const float* wp1 = W + (size_t)(v0 + 16 + col) * Hdim + grp * 8;
  const float* wp2 = W + (size_t)(v0 + 32 + col) * Hdim + grp * 8;
  const float* wp3 = W + (size_t)(v0 + 48 + col) * Hdim + grp * 8;

  bf16x8 aBuf[2][4];
  float4 wBuf[2][8];

  // prologue: S = 0
#pragma unroll
  for (int i = 0; i < 4; ++i)
    aBuf[0][i] = *(const bf16x8*)(abase + i * 1024);
  wBuf[0][0] = *(const float4*)(wp0);     wBuf[0][1] = *(const float4*)(wp0 + 4);
  wBuf[0][2] = *(const float4*)(wp1);     wBuf[0][3] = *(const float4*)(wp1 + 4);
  wBuf[0][4] = *(const float4*)(wp2);     wBuf[0][5] = *(const float4*)(wp2 + 4);
  wBuf[0][6] = *(const float4*)(wp3);     wBuf[0][7] = *(const float4*)(wp3 + 4);

#pragma unroll
  for (int S = 0; S < 16; ++S) {
    const int cur = S & 1, nxt = cur ^ 1;
    if (S < 15) {                        // prefetch S+1 (independent regs)
      const int o = (S + 1) * 32;
#pragma unroll
      for (int i = 0; i < 4; ++i)
        aBuf[nxt][i] = *(const bf16x8*)(abase + (S + 1) * 32768 + i * 1024);
      wBuf[nxt][0] = *(const float4*)(wp0 + o);
      wBuf[nxt][1] = *(const float4*)(wp0 + o + 4);
      wBuf[nxt][2] = *(const float4*)(wp1 + o);
      wBuf[nxt][3] = *(const float4*)(wp1 + o + 4);
      wBuf[nxt][4] = *(const float4*)(wp2 + o);
      wBuf[nxt][5] = *(const float4*)(wp2 + o + 4);
      wBuf[nxt][6] = *(const float4*)(wp3 + o);
      wBuf[nxt][7] = *(const float4*)(wp3 + o + 4);
    }
    bf16x8 bfr[4];
#pragma unroll
    for (int c = 0; c < 4; ++c) {
      const float4 a = wBuf[cur][2 * c], b = wBuf[cur][2 * c + 1];
      u32x4 bw;
      bw.x = pack2(a.x, a.y); bw.y = pack2(a.z, a.w);
      bw.z = pack2(b.x, b.y); bw.w = pack2(b.z, b.w);
      bfr[c] = __builtin_bit_cast(bf16x8, bw);
    }
#pragma unroll
    for (int i = 0; i < 4; ++i)
#pragma unroll
      for (int c = 0; c < 4; ++c)
        acc[i][c] = __builtin_amdgcn_mfma_f32_16x16x32_bf16(
            aBuf[cur][i], bfr[c], acc[i][c], 0, 0, 0);
  }

  // ---- epilogue: 8-stage t-relay ----
  const int T = tsp[0];
  double p9 = 1.0, p8 = 1.0;
  for (int i = 0; i < T; ++i) { p9 *= 0.9; p8 *= 0.8; }
  const float Ps  = (float)p9;                       // 0.9^T
  const float Pm  = (float)p8;                       // 0.8^T
  const float Pms = (float)(0.9 * 10.0 * (p9 - p8)); // s2-coeff into m2
  const float Sws = (float)(10.0 * (1.0 - p9));
  const float Swm = (float)(10.0 * (9.0 * (1.0 - p9) - 4.0 * (1.0 - p8)));

  float bbs[4], bbm[4];
#pragma unroll
  for (int c = 0; c < 4; ++c) {
    const float bb = fc2_b[v0 + c * 16 + col];
    bbs[c] = bb * Sws;
    bbm[c] = bb * Swm;
  }

  for (int s = 0; s < 8; ++s) {
    if (wr == s) {
      float s2[4][4], m2[4][4];          // [cf][hi*2+j]
#pragma unroll
      for (int c = 0; c < 4; ++c)
#pragma unroll
        for (int hi = 0; hi < 2; ++hi)
#pragma unroll
          for (int j = 0; j < 2; ++j) {
            const int b = 8 * hi + 2 * grp + j;
            if (s > 0) {
              const float2 v2 = st[b][c * 16 + col];
              s2[c][hi * 2 + j] = v2.x; m2[c][hi * 2 + j] = v2.y;
            } else {
              s2[c][hi * 2 + j] = 0.f; m2[c][hi * 2 + j] = 0.f;
            }
          }
#pragma unroll
      for (int tt = 0; tt < 2; ++tt) {   // t = 2s + tt
        const int t = 2 * s + tt;
#pragma unroll
        for (int c = 0; c < 4; ++c)
#pragma unroll
          for (int hi = 0; hi < 2; ++hi)
#pragma unroll
            for (int j = 0; j < 2; ++j) {
              const int b  = 8 * hi + 2 * grp + j;
              const int si = hi * 2 + j;
              const float gs = acc[2 * tt + hi][c][2 * j];
              const float gm = acc[2 * tt + hi][c][2 * j + 1];
              const float m2n = Pm * m2[c][si] + Pms * s2[c][si] + gm + bbm[c];
              s2[c][si] = Ps * s2[c][si] + gs + bbs[c];
              m2[c][si] = m2n;
              out[((size_t)b * Sdim + t) * Vdim + v0 + c * 16 + col] =
                  (m2n > THR2f) ? 1.f : 0.f;
            }
      }
#pragma unroll
      for (int c = 0; c < 4; ++c)
#pragma unroll
        for (int hi = 0; hi < 2; ++hi)
#pragma unroll
          for (int j = 0; j < 2; ++j) {
            const int b  = 8 * hi + 2 * grp + j;
            const int si = hi * 2 + j;
            if (s < 7) {
              st[b][c * 16 + col] = make_float2(s2[c][si], m2[c][si]);
            } else {
              syn2[(size_t)b * Vdim + v0 + c * 16 + col] = s2[c][si];
              mem2[(size_t)b * Vdim + v0 + c * 16 + col] = m2[c][si];
            }
          }
    }
    __syncthreads();
  }
}

// ---------------------------------------------------------------------------
extern "C" void kernel_launch(void* const* d_in, const int* in_sizes, int n_in,
                              void* d_out, int out_size, void* d_ws, size_t ws_size,
                              hipStream_t stream) {
  const int*   x       = (const int*)d_in[0];
  const float* embed_w = (const float*)d_in[1];
  const float* fc1_w   = (const float*)d_in[2];
  const float* fc1_b   = (const float*)d_in[3];
  const float* fc2_w   = (const float*)d_in[4];
  const float* fc2_b   = (const float*)d_in[5];
  const float* beta1   = (const float*)d_in[6];
  const int*   tsteps  = (const int*)d_in[7];

  float* out  = (float*)d_out;                          // [16][16][16000]
  float* mem1 = out + (size_t)Bdim * Sdim * Vdim;       // [16][512]
  float* syn2 = mem1 + (size_t)Bdim * Hdim;             // [16][16000]
  float* mem2 = syn2 + (size_t)Bdim * Vdim;             // [16][16000]

  u16* Ab3 = (u16*)d_ws;                                // 512 KB

  snn_prep<<<dim3(8, 4), 256, 0, stream>>>(x, embed_w, fc1_w, fc1_b,
                                           beta1, tsteps, Ab3, mem1);
  snn_fused<<<Vdim / 64, 512, 0, stream>>>(Ab3, fc2_w, fc2_b, tsteps,
                                           out, syn2, mem2);
}

// Round 10
// 155.038 us; speedup vs baseline: 1.0916x; 1.0916x over previous
//
#include <hip/hip_runtime.h>

#define Bdim 16
#define Sdim 16
#define Edim 256
#define Hdim 512
#define Vdim 16000
#define THR1f 0.8f
#define THR2f 1.0f

typedef unsigned int   u32;
typedef unsigned short u16;
typedef __attribute__((ext_vector_type(8))) short bf16x8;
typedef __attribute__((ext_vector_type(4))) float f32x4;

__device__ __forceinline__ u16 f2bf(float f) {          // RNE fp32->bf16
  u32 u = __float_as_uint(f);
  return (u16)((u + 0x7FFFu + ((u >> 16) & 1u)) >> 16);
}
__device__ __forceinline__ u32 pack2(float a, float b) {
  return (u32)f2bf(a) | ((u32)f2bf(b) << 16);
}

// ---------------------------------------------------------------------------
// K1 "pre": ONE launch, grid 4032 x 256.
//  blocks 0..3999   : Wb convert — fc2_w fp32 -> bf16 in B-FRAGMENT layout:
//     value(v,k) -> frag (vb=v>>4, S=k>>5), lane=(v&15)+16*((k>>3)&3), j=k&7
//     byte offset ((vb*16+S)*64+lane)*16 + j*2.
//  blocks 4000..4031: prep = cur1 GEMM (fp32 exact) + m1 recurrence (exact),
//     emitting Ab3 in A-fragment layout (verified R7-R9) + mem1.
// ---------------------------------------------------------------------------
__global__ __launch_bounds__(256) void snn_pre(
    const int* __restrict__ x, const float* __restrict__ embed_w,
    const float* __restrict__ fc1_w, const float* __restrict__ fc1_b,
    const float* __restrict__ W2, const float* __restrict__ beta1p,
    const int* __restrict__ tsp,
    u16* __restrict__ Ab3, u16* __restrict__ Wb, float* __restrict__ mem1)
{
  const int tid = threadIdx.x;

  if (blockIdx.x < 4000) {
    // ---- Wb fragment-layout convert: thread -> (v, kg), 8 elems ----
    const int gid = blockIdx.x * 256 + tid;        // 0..1,023,999
    const int v   = gid >> 6;
    const int kg  = gid & 63;
    const float4* s = (const float4*)(W2 + (size_t)v * Hdim + kg * 8);
    const float4 a = s[0], b = s[1];
    uint4 o;
    o.x = pack2(a.x, a.y); o.y = pack2(a.z, a.w);
    o.z = pack2(b.x, b.y); o.w = pack2(b.z, b.w);
    const size_t dst = ((size_t)((v >> 4) * 16 + (kg >> 2)) * 64 +
                        ((v & 15) + 16 * (kg & 3))) * 16;
    *(uint4*)((char*)Wb + dst) = o;
    return;
  }

  // ---- prep path (blocks 4000..4031), UNCHANGED logic ----
  __shared__ __align__(16) float As[64][68];
  __shared__ __align__(16) float Ws[64][68];
  __shared__ float cbuf[64][68];
  __shared__ int sidx[64];
  const int pb  = blockIdx.x - 4000;     // 0..31
  const int n0  = (pb & 7) * 64;         // h tile
  const int bi0 = (pb >> 3) * 4;         // b tile
  const int tx = tid & 15, ty = tid >> 4;

  if (tid < 64) sidx[tid] = x[(bi0 + (tid & 3)) * Sdim + (tid >> 2)];

  float acc[4][4] = {{0.f}};
  for (int k0 = 0; k0 < Edim; k0 += 64) {
    __syncthreads();                     // also covers sidx on iter 0
#pragma unroll
    for (int i = 0; i < 16; ++i) {
      const int k = tid + i * 256;
      const int rr = k >> 6, j = k & 63;
      As[j][rr] = embed_w[(size_t)sidx[rr] * Edim + k0 + j];
      Ws[j][rr] = fc1_w[(size_t)(n0 + rr) * Edim + k0 + j];
    }
    __syncthreads();
#pragma unroll
    for (int j = 0; j < 64; ++j) {
      const float4 av = *(const float4*)&As[j][ty * 4];
      const float4 wv = *(const float4*)&Ws[j][tx * 4];
      const float a[4] = {av.x, av.y, av.z, av.w};
      const float w[4] = {wv.x, wv.y, wv.z, wv.w};
#pragma unroll
      for (int i = 0; i < 4; ++i)
#pragma unroll
        for (int jj = 0; jj < 4; ++jj)
          acc[i][jj] = fmaf(a[i], w[jj], acc[i][jj]);
    }
  }
#pragma unroll
  for (int i = 0; i < 4; ++i)
#pragma unroll
    for (int jj = 0; jj < 4; ++jj)
      cbuf[ty * 4 + i][tx * 4 + jj] = acc[i][jj] + fc1_b[n0 + tx * 4 + jj];
  __syncthreads();

  const int bb = tid >> 6, hl = tid & 63;
  const int b  = bi0 + bb;
  const int hg = n0 + hl;
  const float b1 = fminf(fmaxf(beta1p[0], 0.f), 1.f);
  const int T = tsp[0];

  double w9T = 1.0, w8T = 1.0;
  for (int i = 0; i < T; ++i) { w9T *= 0.9; w8T *= 0.8; }

  const int S = hg >> 5, q = (hg >> 3) & 3, jc = hg & 7;

  float m1 = 0.f;
  for (int t = 0; t < Sdim; ++t) {
    const float cur = cbuf[t * 4 + bb][hl];
    double p9 = w9T, p8 = w8T;
    float cs = 0.f, cm = 0.f;
    for (int u = 0; u < T; ++u) {
      const float reset = (m1 > THR1f) ? THR1f : 0.f;
      m1 = b1 * m1 + cur - reset;
      if (m1 > THR1f) {
        cs += (float)(p9 * (10.0 / 9.0));
        cm += (float)(10.0 * (p9 - p8));
      }
      p9 *= (10.0 / 9.0);
      p8 *= 1.25;
    }
    int rb = 2 * b;
    int R  = 2 * t + (rb >> 4);
    int l  = q * 16 + (rb & 15);
    Ab3[((size_t)(S * 32 + R) * 64 + l) * 8 + jc] = f2bf(cs);
    rb = 2 * b + 1;
    R  = 2 * t + (rb >> 4);
    l  = q * 16 + (rb & 15);
    Ab3[((size_t)(S * 32 + R) * 64 + l) * 8 + jc] = f2bf(cm);
  }
  mem1[b * Hdim + hg] = m1;
}

// ---------------------------------------------------------------------------
// K2: fused GEMM + Synaptic recurrence + spikes.  v6:
// 500 blocks x 8 waves (512 thr). Wave wr: rows 64wr..64wr+63 (R=4wr+i),
// cols v0..v0+31 (v0=blockIdx*32, 2 col-frags), full K.
// acc[4][2] = 32 VGPR; explicit name-swapped double-buffer (a0/b0 <-> a1/b1,
// no runtime indexing); NO LDS / NO barriers / ~NO VALU in the K-loop
// (Wb pre-converted to bf16 fragments). Epilogue: v5-verified 8-stage
// t-relay (wave wr: t=2wr,2wr+1; b=8hi+2grp+j) via 4 KB LDS.
// ---------------------------------------------------------------------------
__global__ __launch_bounds__(512, 4) void snn_fused(
    const u16* __restrict__ Ab3, const u16* __restrict__ Wb,
    const float* __restrict__ fc2_b, const int* __restrict__ tsp,
    float* __restrict__ out, float* __restrict__ syn2, float* __restrict__ mem2)
{
  __shared__ float2 st[16][32];          // [b][col-local] 4 KB relay state
  const int tid  = threadIdx.x;          // 0..511
  const int lane = tid & 63;
  const int wr   = tid >> 6;             // 0..7: rows 64wr..64wr+63
  const int v0   = blockIdx.x * 32;
  const int col  = lane & 15;
  const int grp  = lane >> 4;

  f32x4 acc[4][2];                       // [i = local R][c = col-frag]
#pragma unroll
  for (int i = 0; i < 4; ++i)
#pragma unroll
    for (int c = 0; c < 2; ++c)
#pragma unroll
      for (int e = 0; e < 4; ++e) acc[i][c][e] = 0.f;

  // A frag (S, R=4wr+i): byte ((S*32+4wr+i)*64+lane)*16
  const char* abase = (const char*)Ab3 + (wr << 12) + lane * 16;
  // B frag (vb=blk*2+c, S): byte ((vb*16+S)*64+lane)*16
  const char* bbase = (const char*)Wb + ((size_t)blockIdx.x << 15) + lane * 16;

  bf16x8 a0[4], a1[4], b0[2], b1[2];
#pragma unroll
  for (int i = 0; i < 4; ++i) a0[i] = *(const bf16x8*)(abase + i * 1024);
#pragma unroll
  for (int c = 0; c < 2; ++c) b0[c] = *(const bf16x8*)(bbase + c * 16384);

#pragma unroll
  for (int Sp = 0; Sp < 16; Sp += 2) {
    // even step: prefetch Sp+1 -> (a1,b1); compute (a0,b0)
#pragma unroll
    for (int i = 0; i < 4; ++i)
      a1[i] = *(const bf16x8*)(abase + (Sp + 1) * 32768 + i * 1024);
#pragma unroll
    for (int c = 0; c < 2; ++c)
      b1[c] = *(const bf16x8*)(bbase + c * 16384 + (Sp + 1) * 1024);
#pragma unroll
    for (int i = 0; i < 4; ++i)
#pragma unroll
      for (int c = 0; c < 2; ++c)
        acc[i][c] = __builtin_amdgcn_mfma_f32_16x16x32_bf16(
            a0[i], b0[c], acc[i][c], 0, 0, 0);
    // odd step: prefetch Sp+2 -> (a0,b0); compute (a1,b1)
    if (Sp + 2 < 16) {
#pragma unroll
      for (int i = 0; i < 4; ++i)
        a0[i] = *(const bf16x8*)(abase + (Sp + 2) * 32768 + i * 1024);
#pragma unroll
      for (int c = 0; c < 2; ++c)
        b0[c] = *(const bf16x8*)(bbase + c * 16384 + (Sp + 2) * 1024);
    }
#pragma unroll
    for (int i = 0; i < 4; ++i)
#pragma unroll
      for (int c = 0; c < 2; ++c)
        acc[i][c] = __builtin_amdgcn_mfma_f32_16x16x32_bf16(
            a1[i], b1[c], acc[i][c], 0, 0, 0);
  }

  // ---- epilogue: 8-stage t-relay (v5-verified mapping) ----
  const int T = tsp[0];
  double p9 = 1.0, p8 = 1.0;
  for (int i = 0; i < T; ++i) { p9 *= 0.9; p8 *= 0.8; }
  const float Ps  = (float)p9;                       // 0.9^T
  const float Pm  = (float)p8;                       // 0.8^T
  const float Pms = (float)(0.9 * 10.0 * (p9 - p8)); // s2-coeff into m2
  const float Sws = (float)(10.0 * (1.0 - p9));
  const float Swm = (float)(10.0 * (9.0 * (1.0 - p9) - 4.0 * (1.0 - p8)));

  float bbs[2], bbm[2];
#pragma unroll
  for (int c = 0; c < 2; ++c) {
    const float bb = fc2_b[v0 + c * 16 + col];
    bbs[c] = bb * Sws;
    bbm[c] = bb * Swm;
  }

  for (int s = 0; s < 8; ++s) {
    if (wr == s) {
      float s2[2][4], m2[2][4];          // [c][hi*2+j]
#pragma unroll
      for (int c = 0; c < 2; ++c)
#pragma unroll
        for (int hi = 0; hi < 2; ++hi)
#pragma unroll
          for (int j = 0; j < 2; ++j) {
            const int b = 8 * hi + 2 * grp + j;
            if (s > 0) {
              const float2 v2 = st[b][c * 16 + col];
              s2[c][hi * 2 + j] = v2.x; m2[c][hi * 2 + j] = v2.y;
            } else {
              s2[c][hi * 2 + j] = 0.f; m2[c][hi * 2 + j] = 0.f;
            }
          }
#pragma unroll
      for (int tt = 0; tt < 2; ++tt) {   // t = 2s + tt
        const int t = 2 * s + tt;
#pragma unroll
        for (int c = 0; c < 2; ++c)
#pragma unroll
          for (int hi = 0; hi < 2; ++hi)
#pragma unroll
            for (int j = 0; j < 2; ++j) {
              const int b  = 8 * hi + 2 * grp + j;
              const int si = hi * 2 + j;
              const float gs = acc[2 * tt + hi][c][2 * j];
              const float gm = acc[2 * tt + hi][c][2 * j + 1];
              const float m2n = Pm * m2[c][si] + Pms * s2[c][si] + gm + bbm[c];
              s2[c][si] = Ps * s2[c][si] + gs + bbs[c];
              m2[c][si] = m2n;
              out[((size_t)b * Sdim + t) * Vdim + v0 + c * 16 + col] =
                  (m2n > THR2f) ? 1.f : 0.f;
            }
      }
#pragma unroll
      for (int c = 0; c < 2; ++c)
#pragma unroll
        for (int hi = 0; hi < 2; ++hi)
#pragma unroll
          for (int j = 0; j < 2; ++j) {
            const int b  = 8 * hi + 2 * grp + j;
            const int si = hi * 2 + j;
            if (s < 7) {
              st[b][c * 16 + col] = make_float2(s2[c][si], m2[c][si]);
            } else {
              syn2[(size_t)b * Vdim + v0 + c * 16 + col] = s2[c][si];
              mem2[(size_t)b * Vdim + v0 + c * 16 + col] = m2[c][si];
            }
          }
    }
    __syncthreads();
  }
}

// ---------------------------------------------------------------------------
extern "C" void kernel_launch(void* const* d_in, const int* in_sizes, int n_in,
                              void* d_out, int out_size, void* d_ws, size_t ws_size,
                              hipStream_t stream) {
  const int*   x       = (const int*)d_in[0];
  const float* embed_w = (const float*)d_in[1];
  const float* fc1_w   = (const float*)d_in[2];
  const float* fc1_b   = (const float*)d_in[3];
  const float* fc2_w   = (const float*)d_in[4];
  const float* fc2_b   = (const float*)d_in[5];
  const float* beta1   = (const float*)d_in[6];
  const int*   tsteps  = (const int*)d_in[7];

  float* out  = (float*)d_out;                          // [16][16][16000]
  float* mem1 = out + (size_t)Bdim * Sdim * Vdim;       // [16][512]
  float* syn2 = mem1 + (size_t)Bdim * Hdim;             // [16][16000]
  float* mem2 = syn2 + (size_t)Bdim * Vdim;             // [16][16000]

  u16* Ab3 = (u16*)d_ws;                                // 512 KB
  u16* Wb  = (u16*)((char*)d_ws + 524288);              // 16,384,000 B

  snn_pre<<<4032, 256, 0, stream>>>(x, embed_w, fc1_w, fc1_b, fc2_w,
                                    beta1, tsteps, Ab3, Wb, mem1);
  snn_fused<<<Vdim / 32, 512, 0, stream>>>(Ab3, Wb, fc2_b, tsteps,
                                           out, syn2, mem2);
}